// Round 1
// baseline (333.670 us; speedup 1.0000x reference)
//
#include <hip/hip_runtime.h>

#define HW    4096
#define LQ    8192
#define DD    256
#define NHEAD 8
#define DHEAD 32

// ---------------------------------------------------------------------------
// Projection GEMM: C[row][n] = sum_k src[row][k] * Bw[k][n] + bias[n]
// src[row][k] = input_{v|i}[b][k][q]  (row = b*LQ + l*HW + q) -- read in place,
// which is naturally K-major -> A tile lands in LDS without a transpose.
// Tiles: BM=64, BN=64, BK=16; 256 threads; 4x4 micro-tile per thread.
// ---------------------------------------------------------------------------
template<int N>
__global__ __launch_bounds__(256) void proj_gemm(const float* __restrict__ in_v,
                                                 const float* __restrict__ in_i,
                                                 const float* __restrict__ Bw,
                                                 const float* __restrict__ bias,
                                                 float* __restrict__ C)
{
    __shared__ float As[16][64];
    __shared__ float Bs[16][64];

    const int m0  = blockIdx.x * 64;
    const int n0  = blockIdx.y * 64;
    const int bi  = m0 >> 13;           // batch
    const int rem = m0 & 8191;
    const float* src = ((rem >> 12) ? in_i : in_v) + bi * (DD * HW);
    const int q0  = rem & 4095;

    const int t  = threadIdx.x;
    const int tx = t & 15;
    const int ty = t >> 4;
    const int lk = t >> 4;              // 0..15  (k within tile)
    const int lq = (t & 15) * 4;        // 0..60  (m or n within tile)

    float acc[4][4] = {};

    for (int k0 = 0; k0 < DD; k0 += 16) {
        const float4 av = *(const float4*)(src + (k0 + lk) * HW + q0 + lq);
        const float4 bv = *(const float4*)(Bw  + (k0 + lk) * N  + n0 + lq);
        __syncthreads();
        *(float4*)&As[lk][lq] = av;
        *(float4*)&Bs[lk][lq] = bv;
        __syncthreads();
#pragma unroll
        for (int kk = 0; kk < 16; ++kk) {
            const float4 a = *(const float4*)&As[kk][ty * 4];
            const float4 b = *(const float4*)&Bs[kk][tx * 4];
            const float avv[4] = {a.x, a.y, a.z, a.w};
            const float bvv[4] = {b.x, b.y, b.z, b.w};
#pragma unroll
            for (int i = 0; i < 4; ++i)
#pragma unroll
                for (int j = 0; j < 4; ++j)
                    acc[i][j] += avv[i] * bvv[j];
        }
    }

    const float4 bb = *(const float4*)(bias + n0 + tx * 4);
#pragma unroll
    for (int i = 0; i < 4; ++i) {
        float4 o;
        o.x = acc[i][0] + bb.x;
        o.y = acc[i][1] + bb.y;
        o.z = acc[i][2] + bb.z;
        o.w = acc[i][3] + bb.w;
        *(float4*)(C + (size_t)(m0 + ty * 4 + i) * N + n0 + tx * 4) = o;
    }
}

// ---------------------------------------------------------------------------
// Sampling: per (b, q) block; thread = (head, d). Softmax over 8 (l,p) logits,
// bilinear-gather value at 4 corners per point, attention-weighted sum.
// value layout: [(b*LQ + l*HW + spatial)][head*32+d]  (row-major, 256 cols)
// ---------------------------------------------------------------------------
__global__ __launch_bounds__(256) void sample_kernel(const float* __restrict__ value,
                                                     const float* __restrict__ offs,
                                                     const float* __restrict__ logits,
                                                     float* __restrict__ fused)
{
    const int row = blockIdx.x;           // b*LQ + ql
    const int b   = row >> 13;
    const int ql  = row & 8191;
    const int pix = ql & 4095;            // reference point repeats across halves
    const float refx = ((pix & 63) + 0.5f) * (1.0f / 64.0f);
    const float refy = ((pix >> 6) + 0.5f) * (1.0f / 64.0f);
    const int head = threadIdx.x >> 5;
    const int d    = threadIdx.x & 31;

    const float* lg = logits + (size_t)row * 64 + head * 8;
    float e[8];
    float mx = lg[0];
#pragma unroll
    for (int j = 1; j < 8; ++j) mx = fmaxf(mx, lg[j]);
    float s = 0.f;
#pragma unroll
    for (int j = 0; j < 8; ++j) { e[j] = __expf(lg[j] - mx); s += e[j]; }
    const float inv = 1.0f / s;

    const float* of = offs + (size_t)row * 128 + head * 16;
    float acc = 0.f;
#pragma unroll
    for (int l = 0; l < 2; ++l) {
        const float* vbase = value + ((size_t)(b * LQ + l * HW) << 8) + head * DHEAD + d;
#pragma unroll
        for (int p = 0; p < 4; ++p) {
            const float ox = of[l * 8 + p * 2];
            const float oy = of[l * 8 + p * 2 + 1];
            const float aw = e[l * 4 + p] * inv;
            // mimic reference arithmetic: x = (ref + off/64)*64 - 0.5
            const float x = (refx + ox * (1.0f / 64.0f)) * 64.0f - 0.5f;
            const float y = (refy + oy * (1.0f / 64.0f)) * 64.0f - 0.5f;
            const float x0f = floorf(x), y0f = floorf(y);
            const int   xi = (int)x0f, yi = (int)y0f;
            const float dx = x - x0f, dy = y - y0f;
            const float w00 = (1.f - dx) * (1.f - dy);
            const float w10 = dx * (1.f - dy);
            const float w01 = (1.f - dx) * dy;
            const float w11 = dx * dy;
            float sv = 0.f;
            if ((unsigned)xi < 64u && (unsigned)yi < 64u)
                sv += w00 * vbase[(size_t)(yi * 64 + xi) << 8];
            if ((unsigned)(xi + 1) < 64u && (unsigned)yi < 64u)
                sv += w10 * vbase[(size_t)(yi * 64 + xi + 1) << 8];
            if ((unsigned)xi < 64u && (unsigned)(yi + 1) < 64u)
                sv += w01 * vbase[(size_t)((yi + 1) * 64 + xi) << 8];
            if ((unsigned)(xi + 1) < 64u && (unsigned)(yi + 1) < 64u)
                sv += w11 * vbase[(size_t)((yi + 1) * 64 + xi + 1) << 8];
            acc += aw * sv;
        }
    }
    fused[((size_t)row << 8) + threadIdx.x] = acc;
}

// ---------------------------------------------------------------------------
// Output GEMM + half-combine + transpose:
// o[b][c][q] = sum_k (fused[b*LQ+q][k] + fused[b*LQ+HW+q][k]) * W_out[k][c]
//              + 2*b_out[c]
// A needs a K-transpose into LDS (fused is k-fastest): scalar stores, padded
// stride 68 keeps it at 2-way (free). Output written as float4 along q.
// ---------------------------------------------------------------------------
__global__ __launch_bounds__(256) void out_gemm(const float* __restrict__ fused,
                                                const float* __restrict__ Wout,
                                                const float* __restrict__ bout,
                                                float* __restrict__ out)
{
    __shared__ float As[16][68];
    __shared__ float Bs[16][64];

    const int m0 = blockIdx.x * 64;       // over B*HW combined rows
    const int c0 = blockIdx.y * 64;
    const int bi = m0 >> 12;
    const int q0 = m0 & 4095;

    const int t  = threadIdx.x;
    const int tx = t & 15;
    const int ty = t >> 4;

    const int mm  = t >> 2;               // 0..63
    const int kk4 = (t & 3) * 4;          // 0,4,8,12
    const int lk  = t >> 4;               // 0..15 (B tile)
    const int ln  = (t & 15) * 4;         // 0..60

    const float* rowv = fused + ((size_t)(bi * LQ + q0 + mm)) * DD;
    const float* rowi = rowv + (size_t)HW * DD;

    float acc[4][4] = {};

    for (int k0 = 0; k0 < DD; k0 += 16) {
        const float4 a1 = *(const float4*)(rowv + k0 + kk4);
        const float4 a2 = *(const float4*)(rowi + k0 + kk4);
        const float4 bv = *(const float4*)(Wout + (size_t)(k0 + lk) * DD + c0 + ln);
        __syncthreads();
        As[kk4 + 0][mm] = a1.x + a2.x;
        As[kk4 + 1][mm] = a1.y + a2.y;
        As[kk4 + 2][mm] = a1.z + a2.z;
        As[kk4 + 3][mm] = a1.w + a2.w;
        *(float4*)&Bs[lk][ln] = bv;
        __syncthreads();
#pragma unroll
        for (int kk = 0; kk < 16; ++kk) {
            const float4 a = *(const float4*)&As[kk][ty * 4];
            const float4 b = *(const float4*)&Bs[kk][tx * 4];
            const float avv[4] = {a.x, a.y, a.z, a.w};
            const float bvv[4] = {b.x, b.y, b.z, b.w};
#pragma unroll
            for (int i = 0; i < 4; ++i)
#pragma unroll
                for (int j = 0; j < 4; ++j)
                    acc[i][j] += avv[i] * bvv[j];
        }
    }

    // transposed write: for each of my 4 columns, the 4 row-values are
    // consecutive q -> one float4 store per column (64B segments per wave).
#pragma unroll
    for (int j = 0; j < 4; ++j) {
        const int c = c0 + tx * 4 + j;
        const float bb = 2.0f * bout[c];
        float4 o;
        o.x = acc[0][j] + bb;
        o.y = acc[1][j] + bb;
        o.z = acc[2][j] + bb;
        o.w = acc[3][j] + bb;
        *(float4*)(out + ((size_t)(bi * DD + c)) * HW + q0 + ty * 4) = o;
    }
}

extern "C" void kernel_launch(void* const* d_in, const int* in_sizes, int n_in,
                              void* d_out, int out_size, void* d_ws, size_t ws_size,
                              hipStream_t stream) {
    const float* in_v    = (const float*)d_in[0];
    const float* in_i    = (const float*)d_in[1];
    const float* W_value = (const float*)d_in[2];
    const float* b_value = (const float*)d_in[3];
    const float* W_off   = (const float*)d_in[4];
    const float* b_off   = (const float*)d_in[5];
    const float* W_attn  = (const float*)d_in[6];
    const float* b_attn  = (const float*)d_in[7];
    const float* W_out   = (const float*)d_in[8];
    const float* b_out   = (const float*)d_in[9];
    float* out = (float*)d_out;

    char* ws = (char*)d_ws;
    float* value_ws = (float*)(ws);                    // 32768*256*4 = 33.55 MB
    float* off_ws   = (float*)(ws + 33554432);         // 32768*128*4 = 16.78 MB
    float* attn_ws  = (float*)(ws + 50331648);         // 32768*64*4  =  8.39 MB
    float* fused_ws = (float*)(ws + 58720256);         // 32768*256*4 = 33.55 MB

    dim3 blk(256);
    proj_gemm<256><<<dim3(512, 4), blk, 0, stream>>>(in_v, in_i, W_value, b_value, value_ws);
    proj_gemm<128><<<dim3(512, 2), blk, 0, stream>>>(in_v, in_i, W_off,   b_off,   off_ws);
    proj_gemm< 64><<<dim3(512, 1), blk, 0, stream>>>(in_v, in_i, W_attn,  b_attn,  attn_ws);
    sample_kernel<<<dim3(32768), blk, 0, stream>>>(value_ws, off_ws, attn_ws, fused_ws);
    out_gemm<<<dim3(256, 4), blk, 0, stream>>>(fused_ws, W_out, b_out, out);
}

// Round 2
// 202.773 us; speedup vs baseline: 1.6455x; 1.6455x over previous
//
#include <hip/hip_runtime.h>

#define HW    4096
#define LQ    8192
#define DD    256
#define NHEAD 8
#define DHEAD 32

// ---------------------------------------------------------------------------
// Projection GEMM: C[row][n] = sum_k src[row][k] * Bw[k][n] + bias[n]
// src[row][k] = input_{v|i}[b][k][q]  (row = b*LQ + l*HW + q) -- read in place,
// which is naturally K-major -> A tile lands in LDS without a transpose.
// Tiles: BM=64, BN=64, BK=16; 256 threads; 4x4 micro-tile per thread.
// ---------------------------------------------------------------------------
template<int N>
__global__ __launch_bounds__(256) void proj_gemm(const float* __restrict__ in_v,
                                                 const float* __restrict__ in_i,
                                                 const float* __restrict__ Bw,
                                                 const float* __restrict__ bias,
                                                 float* __restrict__ C)
{
    __shared__ float As[16][64];
    __shared__ float Bs[16][64];

    const int m0  = blockIdx.x * 64;
    const int n0  = blockIdx.y * 64;
    const int bi  = m0 >> 13;           // batch
    const int rem = m0 & 8191;
    const float* src = ((rem >> 12) ? in_i : in_v) + bi * (DD * HW);
    const int q0  = rem & 4095;

    const int t  = threadIdx.x;
    const int tx = t & 15;
    const int ty = t >> 4;
    const int lk = t >> 4;              // 0..15  (k within tile)
    const int lq = (t & 15) * 4;        // 0..60  (m or n within tile)

    float acc[4][4] = {};

    for (int k0 = 0; k0 < DD; k0 += 16) {
        const float4 av = *(const float4*)(src + (k0 + lk) * HW + q0 + lq);
        const float4 bv = *(const float4*)(Bw  + (k0 + lk) * N  + n0 + lq);
        __syncthreads();
        *(float4*)&As[lk][lq] = av;
        *(float4*)&Bs[lk][lq] = bv;
        __syncthreads();
#pragma unroll
        for (int kk = 0; kk < 16; ++kk) {
            const float4 a = *(const float4*)&As[kk][ty * 4];
            const float4 b = *(const float4*)&Bs[kk][tx * 4];
            const float avv[4] = {a.x, a.y, a.z, a.w};
            const float bvv[4] = {b.x, b.y, b.z, b.w};
#pragma unroll
            for (int i = 0; i < 4; ++i)
#pragma unroll
                for (int j = 0; j < 4; ++j)
                    acc[i][j] += avv[i] * bvv[j];
        }
    }

    const float4 bb = *(const float4*)(bias + n0 + tx * 4);
#pragma unroll
    for (int i = 0; i < 4; ++i) {
        float4 o;
        o.x = acc[i][0] + bb.x;
        o.y = acc[i][1] + bb.y;
        o.z = acc[i][2] + bb.z;
        o.w = acc[i][3] + bb.w;
        *(float4*)(C + (size_t)(m0 + ty * 4 + i) * N + n0 + tx * 4) = o;
    }
}

// ---------------------------------------------------------------------------
// Sampling v2: one WAVE per query. lane = head*8 + d4 (8 heads x 8 float4
// chunks of dhead=32). Softmax + weights duplicated only 8x (vs 32x before);
// gathers are float4 (global_load_dwordx4, 1KB/wave/instr, 4x fewer VMEM
// instrs). Corner guards are branchless: clamped index + zeroed weight --
// exactly the reference's (valid * clipped-gather) semantics.
// ---------------------------------------------------------------------------
__global__ __launch_bounds__(256) void sample_kernel(const float* __restrict__ value,
                                                     const float* __restrict__ offs,
                                                     const float* __restrict__ logits,
                                                     float* __restrict__ fused)
{
    const int row  = (blockIdx.x << 2) + (threadIdx.x >> 6);  // b*LQ + ql
    const int lane = threadIdx.x & 63;
    const int head = lane >> 3;
    const int d4   = (lane & 7) << 2;
    const int b    = row >> 13;
    const int pix  = row & 4095;          // spatial index (ref point repeats)
    const float fx0 = (float)(pix & 63);  // == refx*64 - 0.5 exactly
    const float fy0 = (float)(pix >> 6);

    // softmax over this head's 8 logits
    const float* lg = logits + (size_t)row * 64 + head * 8;
    const float4 lgA = *(const float4*)lg;
    const float4 lgB = *(const float4*)(lg + 4);
    float e[8] = {lgA.x, lgA.y, lgA.z, lgA.w, lgB.x, lgB.y, lgB.z, lgB.w};
    float mx = e[0];
#pragma unroll
    for (int j = 1; j < 8; ++j) mx = fmaxf(mx, e[j]);
    float s = 0.f;
#pragma unroll
    for (int j = 0; j < 8; ++j) { e[j] = __expf(e[j] - mx); s += e[j]; }
    const float inv = 1.0f / s;

    // this head's 16 offset floats
    const float* of = offs + (size_t)row * 128 + head * 16;
    float o[16];
#pragma unroll
    for (int j = 0; j < 4; ++j) {
        const float4 v4 = *(const float4*)(of + j * 4);
        o[j * 4 + 0] = v4.x; o[j * 4 + 1] = v4.y;
        o[j * 4 + 2] = v4.z; o[j * 4 + 3] = v4.w;
    }

    float4 acc = {0.f, 0.f, 0.f, 0.f};
#pragma unroll
    for (int l = 0; l < 2; ++l) {
        const float* vb = value + (((size_t)(b * LQ + l * HW)) << 8) + head * DHEAD + d4;
#pragma unroll
        for (int p = 0; p < 4; ++p) {
            const float ox = o[l * 8 + p * 2];
            const float oy = o[l * 8 + p * 2 + 1];
            const float aw = e[l * 4 + p] * inv;
            const float x = fx0 + ox;
            const float y = fy0 + oy;
            const float xf = floorf(x), yf = floorf(y);
            const int   xi = (int)xf,  yi = (int)yf;
            const float dx = x - xf,   dy = y - yf;
            float w00 = (1.f - dx) * (1.f - dy);
            float w10 = dx * (1.f - dy);
            float w01 = (1.f - dx) * dy;
            float w11 = dx * dy;
            const bool vx0 = (unsigned)xi       < 64u;
            const bool vx1 = (unsigned)(xi + 1) < 64u;
            const bool vy0 = (unsigned)yi       < 64u;
            const bool vy1 = (unsigned)(yi + 1) < 64u;
            w00 = (vx0 && vy0) ? w00 : 0.f;
            w10 = (vx1 && vy0) ? w10 : 0.f;
            w01 = (vx0 && vy1) ? w01 : 0.f;
            w11 = (vx1 && vy1) ? w11 : 0.f;
            const int xc0 = min(max(xi, 0), 63);
            const int xc1 = min(max(xi + 1, 0), 63);
            const int yc0 = min(max(yi, 0), 63) << 6;
            const int yc1 = min(max(yi + 1, 0), 63) << 6;
            const float4 g00 = *(const float4*)(vb + ((size_t)(yc0 + xc0) << 8));
            const float4 g10 = *(const float4*)(vb + ((size_t)(yc0 + xc1) << 8));
            const float4 g01 = *(const float4*)(vb + ((size_t)(yc1 + xc0) << 8));
            const float4 g11 = *(const float4*)(vb + ((size_t)(yc1 + xc1) << 8));
            acc.x += aw * (w00 * g00.x + w10 * g10.x + w01 * g01.x + w11 * g11.x);
            acc.y += aw * (w00 * g00.y + w10 * g10.y + w01 * g01.y + w11 * g11.y);
            acc.z += aw * (w00 * g00.z + w10 * g10.z + w01 * g01.z + w11 * g11.z);
            acc.w += aw * (w00 * g00.w + w10 * g10.w + w01 * g01.w + w11 * g11.w);
        }
    }
    *(float4*)(fused + ((size_t)row << 8) + head * DHEAD + d4) = acc;
}

// ---------------------------------------------------------------------------
// Output GEMM + half-combine + transpose:
// o[b][c][q] = sum_k (fused[b*LQ+q][k] + fused[b*LQ+HW+q][k]) * W_out[k][c]
//              + 2*b_out[c]
// ---------------------------------------------------------------------------
__global__ __launch_bounds__(256) void out_gemm(const float* __restrict__ fused,
                                                const float* __restrict__ Wout,
                                                const float* __restrict__ bout,
                                                float* __restrict__ out)
{
    __shared__ float As[16][68];
    __shared__ float Bs[16][64];

    const int m0 = blockIdx.x * 64;       // over B*HW combined rows
    const int c0 = blockIdx.y * 64;
    const int bi = m0 >> 12;
    const int q0 = m0 & 4095;

    const int t  = threadIdx.x;
    const int tx = t & 15;
    const int ty = t >> 4;

    const int mm  = t >> 2;               // 0..63
    const int kk4 = (t & 3) * 4;          // 0,4,8,12
    const int lk  = t >> 4;               // 0..15 (B tile)
    const int ln  = (t & 15) * 4;         // 0..60

    const float* rowv = fused + ((size_t)(bi * LQ + q0 + mm)) * DD;
    const float* rowi = rowv + (size_t)HW * DD;

    float acc[4][4] = {};

    for (int k0 = 0; k0 < DD; k0 += 16) {
        const float4 a1 = *(const float4*)(rowv + k0 + kk4);
        const float4 a2 = *(const float4*)(rowi + k0 + kk4);
        const float4 bv = *(const float4*)(Wout + (size_t)(k0 + lk) * DD + c0 + ln);
        __syncthreads();
        As[kk4 + 0][mm] = a1.x + a2.x;
        As[kk4 + 1][mm] = a1.y + a2.y;
        As[kk4 + 2][mm] = a1.z + a2.z;
        As[kk4 + 3][mm] = a1.w + a2.w;
        *(float4*)&Bs[lk][ln] = bv;
        __syncthreads();
#pragma unroll
        for (int kk = 0; kk < 16; ++kk) {
            const float4 a = *(const float4*)&As[kk][ty * 4];
            const float4 b = *(const float4*)&Bs[kk][tx * 4];
            const float avv[4] = {a.x, a.y, a.z, a.w};
            const float bvv[4] = {b.x, b.y, b.z, b.w};
#pragma unroll
            for (int i = 0; i < 4; ++i)
#pragma unroll
                for (int j = 0; j < 4; ++j)
                    acc[i][j] += avv[i] * bvv[j];
        }
    }

#pragma unroll
    for (int j = 0; j < 4; ++j) {
        const int c = c0 + tx * 4 + j;
        const float bb = 2.0f * bout[c];
        float4 o;
        o.x = acc[0][j] + bb;
        o.y = acc[1][j] + bb;
        o.z = acc[2][j] + bb;
        o.w = acc[3][j] + bb;
        *(float4*)(out + ((size_t)(bi * DD + c)) * HW + q0 + ty * 4) = o;
    }
}

extern "C" void kernel_launch(void* const* d_in, const int* in_sizes, int n_in,
                              void* d_out, int out_size, void* d_ws, size_t ws_size,
                              hipStream_t stream) {
    const float* in_v    = (const float*)d_in[0];
    const float* in_i    = (const float*)d_in[1];
    const float* W_value = (const float*)d_in[2];
    const float* b_value = (const float*)d_in[3];
    const float* W_off   = (const float*)d_in[4];
    const float* b_off   = (const float*)d_in[5];
    const float* W_attn  = (const float*)d_in[6];
    const float* b_attn  = (const float*)d_in[7];
    const float* W_out   = (const float*)d_in[8];
    const float* b_out   = (const float*)d_in[9];
    float* out = (float*)d_out;

    char* ws = (char*)d_ws;
    float* value_ws = (float*)(ws);                    // 32768*256*4 = 33.55 MB
    float* off_ws   = (float*)(ws + 33554432);         // 32768*128*4 = 16.78 MB
    float* attn_ws  = (float*)(ws + 50331648);         // 32768*64*4  =  8.39 MB
    float* fused_ws = (float*)(ws + 58720256);         // 32768*256*4 = 33.55 MB

    dim3 blk(256);
    proj_gemm<256><<<dim3(512, 4), blk, 0, stream>>>(in_v, in_i, W_value, b_value, value_ws);
    proj_gemm<128><<<dim3(512, 2), blk, 0, stream>>>(in_v, in_i, W_off,   b_off,   off_ws);
    proj_gemm< 64><<<dim3(512, 1), blk, 0, stream>>>(in_v, in_i, W_attn,  b_attn,  attn_ws);
    sample_kernel<<<dim3(8192), blk, 0, stream>>>(value_ws, off_ws, attn_ws, fused_ws);
    out_gemm<<<dim3(256, 4), blk, 0, stream>>>(fused_ws, W_out, b_out, out);
}

// Round 3
// 95.147 us; speedup vs baseline: 3.5069x; 2.1311x over previous
//
#include <hip/hip_runtime.h>

#define HW 4096
#define LQ 8192
#define DD 256

typedef __bf16 bf16x8 __attribute__((ext_vector_type(8)));
typedef __bf16 bf16x4 __attribute__((ext_vector_type(4)));
typedef float  f32x4  __attribute__((ext_vector_type(4)));

// async global->LDS, 16B per lane; LDS dest is wave-uniform base + lane*16
#define GLOAD16(g, l) __builtin_amdgcn_global_load_lds(                     \
    (__attribute__((address_space(1))) void*)(g),                          \
    (__attribute__((address_space(3))) void*)(l), 16, 0, 0)

// ---------------------------------------------------------------------------
// prep_src: input [b][k][q] fp32 -> srcS bf16 [row=b*8192+l*4096+q][k=256],
// rows 512B, each row XOR-swizzled in 16B granules: byte ^= ((row&7)<<4).
// LDS-tiled transpose, 64k x 64q per block.
// ---------------------------------------------------------------------------
__global__ __launch_bounds__(256) void prep_src(const float* __restrict__ in_v,
                                                const float* __restrict__ in_i,
                                                char* __restrict__ srcS)
{
    __shared__ float tile[64][68];
    const int q0 = blockIdx.x * 64;
    const int k0 = blockIdx.y * 64;
    const int bz = blockIdx.z;                    // b*2 + l
    const float* src = ((bz & 1) ? in_i : in_v) + (size_t)(bz >> 1) * (DD * HW);
    const int t  = threadIdx.x;
    const int ql = (t & 15) * 4;
    const int kl = t >> 4;
#pragma unroll
    for (int rr = 0; rr < 4; ++rr) {
        const float4 v = *(const float4*)(src + (size_t)(k0 + kl + rr * 16) * HW + q0 + ql);
        *(float4*)&tile[kl + rr * 16][ql] = v;
    }
    __syncthreads();
    const int qrow = t >> 2;
    const int kc   = (t & 3) * 16;               // k-chunk (floats) within 64
    const int row  = (bz >> 1) * LQ + (bz & 1) * HW + q0 + qrow;
    bf16x8 p0, p1;
#pragma unroll
    for (int j = 0; j < 8; ++j) {
        p0[j] = (__bf16)tile[kc + j][qrow];
        p1[j] = (__bf16)tile[kc + 8 + j][qrow];
    }
    char* drow = srcS + (size_t)row * 512;
    const int sw   = (row & 7) << 4;
    const int base = k0 * 2 + kc * 2;
    *(bf16x8*)(drow + ((base)      ^ sw)) = p0;
    *(bf16x8*)(drow + ((base + 16) ^ sw)) = p1;
}

// ---------------------------------------------------------------------------
// prep_w: weights -> transposed bf16, swizzled rows.
// WcatT [448 rows n][256 k] (rows 512B): n<256 W_value, <384 W_off, else W_attn
// WoutT [256 rows c][512 k'] (rows 1024B): k'<256 -> W_out[k'][c], else W_out[k'-256][c]
// ---------------------------------------------------------------------------
__global__ __launch_bounds__(256) void prep_w(const float* __restrict__ Wv,
                                              const float* __restrict__ Wo,
                                              const float* __restrict__ Wa,
                                              const float* __restrict__ Wout,
                                              char* __restrict__ WcatT,
                                              char* __restrict__ WoutT)
{
    const int gi = blockIdx.x * 256 + threadIdx.x;
    if (gi < 448 * 32) {
        const int row = gi >> 5;
        const int g   = gi & 31;
        const int k   = g * 8;
        const float* col; int stride;
        if (row < 256)      { col = Wv + row;         stride = 256; }
        else if (row < 384) { col = Wo + (row - 256); stride = 128; }
        else                { col = Wa + (row - 384); stride = 64;  }
        bf16x8 p;
#pragma unroll
        for (int j = 0; j < 8; ++j) p[j] = (__bf16)col[(size_t)(k + j) * stride];
        char* d = WcatT + (size_t)row * 512;
        *(bf16x8*)(d + ((g * 16) ^ ((row & 7) << 4))) = p;
    } else {
        const int gj = gi - 448 * 32;
        if (gj >= 256 * 64) return;
        const int c = gj >> 6;
        const int g = gj & 63;
        const int k = (g * 8) & 255;              // k' mod 256 (granule never straddles)
        bf16x8 p;
#pragma unroll
        for (int j = 0; j < 8; ++j) p[j] = (__bf16)Wout[(size_t)(k + j) * 256 + c];
        char* d = WoutT + (size_t)c * 1024;
        *(bf16x8*)(d + ((g * 16) ^ ((c & 7) << 4))) = p;
    }
}

// ---------------------------------------------------------------------------
// Fused projection GEMM (MFMA): C[32768 x 448] = srcS @ WcatT^T, K=256.
// BM=128, BN=64, BK=64; 4 waves in 2x2; wave tile 64x32; 16x16x32 bf16 MFMA.
// Staging: global_load_lds x16B from pre-swizzled global -> linear LDS.
// Frag reads: ds_read_b128 at swizzled offset (conflict-free).
// Outputs split to value (N256, fp32), off (N128), attn (N64) + bias.
// ---------------------------------------------------------------------------
__global__ __launch_bounds__(256) void mfma_proj(const char* __restrict__ srcS,
                                                 const char* __restrict__ WcatT,
                                                 const float* __restrict__ b_value,
                                                 const float* __restrict__ b_off,
                                                 const float* __restrict__ b_attn,
                                                 float* __restrict__ value,
                                                 float* __restrict__ off,
                                                 float* __restrict__ attn)
{
    __shared__ char smem[24576];
    char* As = smem;            // 128 rows x 128B
    char* Bs = smem + 16384;    // 64 rows x 128B

    const int M0 = blockIdx.x * 128;
    const int N0 = blockIdx.y * 64;
    const int t = threadIdx.x;
    const int w = t >> 6;
    const int l = t & 63;
    const int lm = l & 15, lk = l >> 4;
    const int wave_m = (w >> 1) * 64;
    const int wave_n = (w & 1) * 32;

    f32x4 acc[4][2] = {};

    const char* Ab = As + (wave_m + lm) * 128;
    const char* Bb = Bs + (wave_n + lm) * 128;
    const int go0 = (lk ^ (l & 7)) * 16;   // inner k32 #0 granule (swizzled)
    const int go1 = go0 ^ 64;              // inner k32 #1

    for (int kt = 0; kt < 4; ++kt) {
        __syncthreads();
        const int kb = kt * 128;
#pragma unroll
        for (int c = 0; c < 4; ++c) {
            const char* g = srcS + (size_t)(M0 + w * 32 + c * 8 + (l >> 3)) * 512 + kb + (l & 7) * 16;
            GLOAD16(g, As + (w * 4 + c) * 1024);
        }
#pragma unroll
        for (int c = 0; c < 2; ++c) {
            const char* g = WcatT + (size_t)(N0 + w * 16 + c * 8 + (l >> 3)) * 512 + kb + (l & 7) * 16;
            GLOAD16(g, Bs + (w * 2 + c) * 1024);
        }
        __syncthreads();

        bf16x8 af[4], bb[2];
#pragma unroll
        for (int mi = 0; mi < 4; ++mi) af[mi] = *(const bf16x8*)(Ab + mi * 2048 + go0);
#pragma unroll
        for (int ni = 0; ni < 2; ++ni) bb[ni] = *(const bf16x8*)(Bb + ni * 2048 + go0);
#pragma unroll
        for (int mi = 0; mi < 4; ++mi)
#pragma unroll
            for (int ni = 0; ni < 2; ++ni)
                acc[mi][ni] = __builtin_amdgcn_mfma_f32_16x16x32_bf16(af[mi], bb[ni], acc[mi][ni], 0, 0, 0);
#pragma unroll
        for (int mi = 0; mi < 4; ++mi) af[mi] = *(const bf16x8*)(Ab + mi * 2048 + go1);
#pragma unroll
        for (int ni = 0; ni < 2; ++ni) bb[ni] = *(const bf16x8*)(Bb + ni * 2048 + go1);
#pragma unroll
        for (int mi = 0; mi < 4; ++mi)
#pragma unroll
            for (int ni = 0; ni < 2; ++ni)
                acc[mi][ni] = __builtin_amdgcn_mfma_f32_16x16x32_bf16(af[mi], bb[ni], acc[mi][ni], 0, 0, 0);
    }

    float* outp; const float* bias; int ncols, nloc;
    if (N0 < 256)      { outp = value; bias = b_value; ncols = 256; nloc = N0; }
    else if (N0 < 384) { outp = off;   bias = b_off;   ncols = 128; nloc = N0 - 256; }
    else               { outp = attn;  bias = b_attn;  ncols = 64;  nloc = N0 - 384; }

#pragma unroll
    for (int ni = 0; ni < 2; ++ni) {
        const int cl = nloc + wave_n + ni * 16 + lm;
        const float bv = bias[cl];
#pragma unroll
        for (int mi = 0; mi < 4; ++mi) {
            const int row = M0 + wave_m + mi * 16 + lk * 4;
#pragma unroll
            for (int r = 0; r < 4; ++r)
                outp[(size_t)(row + r) * ncols + cl] = acc[mi][ni][r] + bv;
        }
    }
}

// ---------------------------------------------------------------------------
// Sampling: one wave per query; lane = head*8 + d4. float4 gathers from fp32
// value; writes fused as bf16 (8B, swizzled row layout for mfma_out staging).
// ---------------------------------------------------------------------------
__global__ __launch_bounds__(256) void sample_kernel(const float* __restrict__ value,
                                                     const float* __restrict__ offs,
                                                     const float* __restrict__ logits,
                                                     char* __restrict__ fusedS)
{
    const int row  = (blockIdx.x << 2) + (threadIdx.x >> 6);  // b*LQ + ql
    const int lane = threadIdx.x & 63;
    const int head = lane >> 3;
    const int d4   = (lane & 7) << 2;
    const int b    = row >> 13;
    const int pix  = row & 4095;
    const float fx0 = (float)(pix & 63);
    const float fy0 = (float)(pix >> 6);

    const float* lg = logits + (size_t)row * 64 + head * 8;
    const float4 lgA = *(const float4*)lg;
    const float4 lgB = *(const float4*)(lg + 4);
    float e[8] = {lgA.x, lgA.y, lgA.z, lgA.w, lgB.x, lgB.y, lgB.z, lgB.w};
    float mx = e[0];
#pragma unroll
    for (int j = 1; j < 8; ++j) mx = fmaxf(mx, e[j]);
    float s = 0.f;
#pragma unroll
    for (int j = 0; j < 8; ++j) { e[j] = __expf(e[j] - mx); s += e[j]; }
    const float inv = 1.0f / s;

    const float* of = offs + (size_t)row * 128 + head * 16;
    float o[16];
#pragma unroll
    for (int j = 0; j < 4; ++j) {
        const float4 v4 = *(const float4*)(of + j * 4);
        o[j * 4 + 0] = v4.x; o[j * 4 + 1] = v4.y;
        o[j * 4 + 2] = v4.z; o[j * 4 + 3] = v4.w;
    }

    float4 acc = {0.f, 0.f, 0.f, 0.f};
#pragma unroll
    for (int ll = 0; ll < 2; ++ll) {
        const float* vb = value + (((size_t)(b * LQ + ll * HW)) << 8) + head * 32 + d4;
#pragma unroll
        for (int p = 0; p < 4; ++p) {
            const float ox = o[ll * 8 + p * 2];
            const float oy = o[ll * 8 + p * 2 + 1];
            const float aw = e[ll * 4 + p] * inv;
            const float x = fx0 + ox;
            const float y = fy0 + oy;
            const float xf = floorf(x), yf = floorf(y);
            const int   xi = (int)xf,  yi = (int)yf;
            const float dx = x - xf,   dy = y - yf;
            float w00 = (1.f - dx) * (1.f - dy);
            float w10 = dx * (1.f - dy);
            float w01 = (1.f - dx) * dy;
            float w11 = dx * dy;
            const bool vx0 = (unsigned)xi       < 64u;
            const bool vx1 = (unsigned)(xi + 1) < 64u;
            const bool vy0 = (unsigned)yi       < 64u;
            const bool vy1 = (unsigned)(yi + 1) < 64u;
            w00 = (vx0 && vy0) ? w00 : 0.f;
            w10 = (vx1 && vy0) ? w10 : 0.f;
            w01 = (vx0 && vy1) ? w01 : 0.f;
            w11 = (vx1 && vy1) ? w11 : 0.f;
            const int xc0 = min(max(xi, 0), 63);
            const int xc1 = min(max(xi + 1, 0), 63);
            const int yc0 = min(max(yi, 0), 63) << 6;
            const int yc1 = min(max(yi + 1, 0), 63) << 6;
            const float4 g00 = *(const float4*)(vb + ((size_t)(yc0 + xc0) << 8));
            const float4 g10 = *(const float4*)(vb + ((size_t)(yc0 + xc1) << 8));
            const float4 g01 = *(const float4*)(vb + ((size_t)(yc1 + xc0) << 8));
            const float4 g11 = *(const float4*)(vb + ((size_t)(yc1 + xc1) << 8));
            acc.x += aw * (w00 * g00.x + w10 * g10.x + w01 * g01.x + w11 * g11.x);
            acc.y += aw * (w00 * g00.y + w10 * g10.y + w01 * g01.y + w11 * g11.y);
            acc.z += aw * (w00 * g00.z + w10 * g10.z + w01 * g01.z + w11 * g11.z);
            acc.w += aw * (w00 * g00.w + w10 * g10.w + w01 * g01.w + w11 * g11.w);
        }
    }
    bf16x4 ov = {(__bf16)acc.x, (__bf16)acc.y, (__bf16)acc.z, (__bf16)acc.w};
    const int bo = (head * 64 + d4 * 2) ^ ((row & 7) << 4);
    *(bf16x4*)(fusedS + (size_t)row * 512 + bo) = ov;
}

// ---------------------------------------------------------------------------
// Output GEMM (MFMA): out[b][c][q] = sum_{k'=0..511} A'[q][k'] WoutT[c][k']
//  + 2*b_out[c], where A'[q][k'] = fusedS[b*8192 + (k'>=256)*4096 + q][k'&255]
// (the v+i half-sum absorbed as K-concatenation). M=16384, N=256, K=512.
// Epilogue: LDS transpose -> coalesced fp32 stores along q.
// ---------------------------------------------------------------------------
__global__ __launch_bounds__(256) void mfma_out(const char* __restrict__ fusedS,
                                                const char* __restrict__ WoutT,
                                                const float* __restrict__ b_out,
                                                float* __restrict__ out)
{
    __shared__ char smem[24576];
    char* As = smem;
    char* Bs = smem + 16384;
    float* Tr = (float*)smem;   // 64 x 68 fp32, aliases As/Bs after K-loop

    const int M0 = blockIdx.x * 128;
    const int N0 = blockIdx.y * 64;
    const int bi = M0 >> 12;
    const int q0 = M0 & 4095;
    const int t = threadIdx.x;
    const int w = t >> 6;
    const int l = t & 63;
    const int lm = l & 15, lk = l >> 4;
    const int wave_m = (w >> 1) * 64;
    const int wave_n = (w & 1) * 32;

    f32x4 acc[4][2] = {};

    const char* Ab = As + (wave_m + lm) * 128;
    const char* Bb = Bs + (wave_n + lm) * 128;
    const int go0 = (lk ^ (l & 7)) * 16;
    const int go1 = go0 ^ 64;

    for (int kt = 0; kt < 8; ++kt) {
        __syncthreads();
        const int half = kt >> 2;
        const int kb   = (kt & 3) * 128;
#pragma unroll
        for (int c = 0; c < 4; ++c) {
            const char* g = fusedS + (size_t)(bi * LQ + half * HW + q0 + w * 32 + c * 8 + (l >> 3)) * 512
                          + kb + (l & 7) * 16;
            GLOAD16(g, As + (w * 4 + c) * 1024);
        }
#pragma unroll
        for (int c = 0; c < 2; ++c) {
            const char* g = WoutT + (size_t)(N0 + w * 16 + c * 8 + (l >> 3)) * 1024 + kt * 128 + (l & 7) * 16;
            GLOAD16(g, Bs + (w * 2 + c) * 1024);
        }
        __syncthreads();

        bf16x8 af[4], bb[2];
#pragma unroll
        for (int mi = 0; mi < 4; ++mi) af[mi] = *(const bf16x8*)(Ab + mi * 2048 + go0);
#pragma unroll
        for (int ni = 0; ni < 2; ++ni) bb[ni] = *(const bf16x8*)(Bb + ni * 2048 + go0);
#pragma unroll
        for (int mi = 0; mi < 4; ++mi)
#pragma unroll
            for (int ni = 0; ni < 2; ++ni)
                acc[mi][ni] = __builtin_amdgcn_mfma_f32_16x16x32_bf16(af[mi], bb[ni], acc[mi][ni], 0, 0, 0);
#pragma unroll
        for (int mi = 0; mi < 4; ++mi) af[mi] = *(const bf16x8*)(Ab + mi * 2048 + go1);
#pragma unroll
        for (int ni = 0; ni < 2; ++ni) bb[ni] = *(const bf16x8*)(Bb + ni * 2048 + go1);
#pragma unroll
        for (int mi = 0; mi < 4; ++mi)
#pragma unroll
            for (int ni = 0; ni < 2; ++ni)
                acc[mi][ni] = __builtin_amdgcn_mfma_f32_16x16x32_bf16(af[mi], bb[ni], acc[mi][ni], 0, 0, 0);
    }

    float bias2[2];
#pragma unroll
    for (int ni = 0; ni < 2; ++ni) bias2[ni] = 2.0f * b_out[N0 + wave_n + ni * 16 + lm];

#pragma unroll
    for (int h = 0; h < 2; ++h) {
        __syncthreads();
        if ((w >> 1) == h) {
#pragma unroll
            for (int mi = 0; mi < 4; ++mi)
#pragma unroll
                for (int ni = 0; ni < 2; ++ni)
#pragma unroll
                    for (int r = 0; r < 4; ++r)
                        Tr[(wave_n + ni * 16 + lm) * 68 + mi * 16 + lk * 4 + r] = acc[mi][ni][r] + bias2[ni];
        }
        __syncthreads();
        const int c  = t >> 2;
        const int qo = (t & 3) * 16;
        float* dst = out + ((size_t)(bi * DD + N0 + c)) * HW + q0 + h * 64 + qo;
        const float* sp = Tr + c * 68 + qo;
#pragma unroll
        for (int j = 0; j < 4; ++j)
            *(f32x4*)(dst + j * 4) = *(const f32x4*)(sp + j * 4);
    }
}

extern "C" void kernel_launch(void* const* d_in, const int* in_sizes, int n_in,
                              void* d_out, int out_size, void* d_ws, size_t ws_size,
                              hipStream_t stream) {
    const float* in_v    = (const float*)d_in[0];
    const float* in_i    = (const float*)d_in[1];
    const float* W_value = (const float*)d_in[2];
    const float* b_value = (const float*)d_in[3];
    const float* W_off   = (const float*)d_in[4];
    const float* b_off   = (const float*)d_in[5];
    const float* W_attn  = (const float*)d_in[6];
    const float* b_attn  = (const float*)d_in[7];
    const float* W_out   = (const float*)d_in[8];
    const float* b_out   = (const float*)d_in[9];
    float* out = (float*)d_out;

    char* ws = (char*)d_ws;
    float* value_ws = (float*)(ws);                 // 33.55 MB fp32
    float* off_ws   = (float*)(ws + 33554432);      // 16.78 MB fp32
    float* attn_ws  = (float*)(ws + 50331648);      //  8.39 MB fp32
    char*  srcS     = ws + 58720256;                // 16.78 MB bf16 [32768][512B]
    char*  fusedS   = ws + 75497472;                // 16.78 MB bf16 [32768][512B]
    char*  WcatT    = ws + 92274688;                // 229 KB  bf16 [448][512B]
    char*  WoutT    = ws + 92504064;                // 256 KB  bf16 [256][1024B]

    prep_src<<<dim3(64, 4, 8), 256, 0, stream>>>(in_v, in_i, srcS);
    prep_w<<<120, 256, 0, stream>>>(W_value, W_off, W_attn, W_out, WcatT, WoutT);
    mfma_proj<<<dim3(256, 7), 256, 0, stream>>>(srcS, WcatT, b_value, b_off, b_attn,
                                                value_ws, off_ws, attn_ws);
    sample_kernel<<<dim3(8192), 256, 0, stream>>>(value_ws, off_ws, attn_ws, fusedS);
    mfma_out<<<dim3(128, 4), 256, 0, stream>>>(fusedS, WoutT, b_out, out);
}

// Round 4
// 81.318 us; speedup vs baseline: 4.1033x; 1.1701x over previous
//
#include <hip/hip_runtime.h>

#define HW 4096
#define LQ 8192
#define DD 256

typedef __bf16 bf16x8 __attribute__((ext_vector_type(8)));
typedef float  f32x4  __attribute__((ext_vector_type(4)));
typedef unsigned int u32;
typedef u32 u32x4 __attribute__((ext_vector_type(4)));

// async global->LDS, 16B per lane; LDS dest is wave-uniform base + lane*16
#define GLOAD16(g, l) __builtin_amdgcn_global_load_lds(                     \
    (__attribute__((address_space(1))) void*)(g),                          \
    (__attribute__((address_space(3))) void*)(l), 16, 0, 0)

// ---------------------------------------------------------------------------
// prep_src: input [b][k][q] fp32 -> srcS bf16 [row=b*8192+l*4096+q][k=256],
// rows 512B, each row XOR-swizzled in 16B granules: byte ^= ((row&7)<<4).
// ---------------------------------------------------------------------------
__global__ __launch_bounds__(256) void prep_src(const float* __restrict__ in_v,
                                                const float* __restrict__ in_i,
                                                char* __restrict__ srcS)
{
    __shared__ float tile[64][68];
    const int q0 = blockIdx.x * 64;
    const int k0 = blockIdx.y * 64;
    const int bz = blockIdx.z;                    // b*2 + l
    const float* src = ((bz & 1) ? in_i : in_v) + (size_t)(bz >> 1) * (DD * HW);
    const int t  = threadIdx.x;
    const int ql = (t & 15) * 4;
    const int kl = t >> 4;
#pragma unroll
    for (int rr = 0; rr < 4; ++rr) {
        const float4 v = *(const float4*)(src + (size_t)(k0 + kl + rr * 16) * HW + q0 + ql);
        *(float4*)&tile[kl + rr * 16][ql] = v;
    }
    __syncthreads();
    const int qrow = t >> 2;
    const int kc   = (t & 3) * 16;
    const int row  = (bz >> 1) * LQ + (bz & 1) * HW + q0 + qrow;
    bf16x8 p0, p1;
#pragma unroll
    for (int j = 0; j < 8; ++j) {
        p0[j] = (__bf16)tile[kc + j][qrow];
        p1[j] = (__bf16)tile[kc + 8 + j][qrow];
    }
    char* drow = srcS + (size_t)row * 512;
    const int sw   = (row & 7) << 4;
    const int base = k0 * 2 + kc * 2;
    *(bf16x8*)(drow + ((base)      ^ sw)) = p0;
    *(bf16x8*)(drow + ((base + 16) ^ sw)) = p1;
}

// ---------------------------------------------------------------------------
// prep_w: weights -> transposed bf16, swizzled rows.
// ---------------------------------------------------------------------------
__global__ __launch_bounds__(256) void prep_w(const float* __restrict__ Wv,
                                              const float* __restrict__ Wo,
                                              const float* __restrict__ Wa,
                                              const float* __restrict__ Wout,
                                              char* __restrict__ WcatT,
                                              char* __restrict__ WoutT)
{
    const int gi = blockIdx.x * 256 + threadIdx.x;
    if (gi < 448 * 32) {
        const int row = gi >> 5;
        const int g   = gi & 31;
        const int k   = g * 8;
        const float* col; int stride;
        if (row < 256)      { col = Wv + row;         stride = 256; }
        else if (row < 384) { col = Wo + (row - 256); stride = 128; }
        else                { col = Wa + (row - 384); stride = 64;  }
        bf16x8 p;
#pragma unroll
        for (int j = 0; j < 8; ++j) p[j] = (__bf16)col[(size_t)(k + j) * stride];
        char* d = WcatT + (size_t)row * 512;
        *(bf16x8*)(d + ((g * 16) ^ ((row & 7) << 4))) = p;
    } else {
        const int gj = gi - 448 * 32;
        if (gj >= 256 * 64) return;
        const int c = gj >> 6;
        const int g = gj & 63;
        const int k = (g * 8) & 255;
        bf16x8 p;
#pragma unroll
        for (int j = 0; j < 8; ++j) p[j] = (__bf16)Wout[(size_t)(k + j) * 256 + c];
        char* d = WoutT + (size_t)c * 1024;
        *(bf16x8*)(d + ((g * 16) ^ ((c & 7) << 4))) = p;
    }
}

// ---------------------------------------------------------------------------
// Fused projection GEMM (MFMA): C[32768 x 448] = srcS @ WcatT^T, K=256.
// value output written as bf16 [row][256] (rows 512B, linear); off/attn fp32.
// ---------------------------------------------------------------------------
__global__ __launch_bounds__(256) void mfma_proj(const char* __restrict__ srcS,
                                                 const char* __restrict__ WcatT,
                                                 const float* __restrict__ b_value,
                                                 const float* __restrict__ b_off,
                                                 const float* __restrict__ b_attn,
                                                 __bf16* __restrict__ valueB,
                                                 float* __restrict__ off,
                                                 float* __restrict__ attn)
{
    __shared__ char smem[24576];
    char* As = smem;            // 128 rows x 128B
    char* Bs = smem + 16384;    // 64 rows x 128B

    const int M0 = blockIdx.x * 128;
    const int N0 = blockIdx.y * 64;
    const int t = threadIdx.x;
    const int w = t >> 6;
    const int l = t & 63;
    const int lm = l & 15, lk = l >> 4;
    const int wave_m = (w >> 1) * 64;
    const int wave_n = (w & 1) * 32;

    f32x4 acc[4][2] = {};

    const char* Ab = As + (wave_m + lm) * 128;
    const char* Bb = Bs + (wave_n + lm) * 128;
    const int go0 = (lk ^ (l & 7)) * 16;
    const int go1 = go0 ^ 64;

    for (int kt = 0; kt < 4; ++kt) {
        __syncthreads();
        const int kb = kt * 128;
#pragma unroll
        for (int c = 0; c < 4; ++c) {
            const char* g = srcS + (size_t)(M0 + w * 32 + c * 8 + (l >> 3)) * 512 + kb + (l & 7) * 16;
            GLOAD16(g, As + (w * 4 + c) * 1024);
        }
#pragma unroll
        for (int c = 0; c < 2; ++c) {
            const char* g = WcatT + (size_t)(N0 + w * 16 + c * 8 + (l >> 3)) * 512 + kb + (l & 7) * 16;
            GLOAD16(g, Bs + (w * 2 + c) * 1024);
        }
        __syncthreads();

        bf16x8 af[4], bb[2];
#pragma unroll
        for (int mi = 0; mi < 4; ++mi) af[mi] = *(const bf16x8*)(Ab + mi * 2048 + go0);
#pragma unroll
        for (int ni = 0; ni < 2; ++ni) bb[ni] = *(const bf16x8*)(Bb + ni * 2048 + go0);
#pragma unroll
        for (int mi = 0; mi < 4; ++mi)
#pragma unroll
            for (int ni = 0; ni < 2; ++ni)
                acc[mi][ni] = __builtin_amdgcn_mfma_f32_16x16x32_bf16(af[mi], bb[ni], acc[mi][ni], 0, 0, 0);
#pragma unroll
        for (int mi = 0; mi < 4; ++mi) af[mi] = *(const bf16x8*)(Ab + mi * 2048 + go1);
#pragma unroll
        for (int ni = 0; ni < 2; ++ni) bb[ni] = *(const bf16x8*)(Bb + ni * 2048 + go1);
#pragma unroll
        for (int mi = 0; mi < 4; ++mi)
#pragma unroll
            for (int ni = 0; ni < 2; ++ni)
                acc[mi][ni] = __builtin_amdgcn_mfma_f32_16x16x32_bf16(af[mi], bb[ni], acc[mi][ni], 0, 0, 0);
    }

    if (N0 < 256) {
#pragma unroll
        for (int ni = 0; ni < 2; ++ni) {
            const int cl = N0 + wave_n + ni * 16 + lm;
            const float bv = b_value[cl];
#pragma unroll
            for (int mi = 0; mi < 4; ++mi) {
                const int row = M0 + wave_m + mi * 16 + lk * 4;
#pragma unroll
                for (int r = 0; r < 4; ++r)
                    valueB[(size_t)(row + r) * 256 + cl] = (__bf16)(acc[mi][ni][r] + bv);
            }
        }
    } else {
        float* outp; const float* bias; int ncols, nloc;
        if (N0 < 384) { outp = off;  bias = b_off;  ncols = 128; nloc = N0 - 256; }
        else          { outp = attn; bias = b_attn; ncols = 64;  nloc = N0 - 384; }
#pragma unroll
        for (int ni = 0; ni < 2; ++ni) {
            const int cl = nloc + wave_n + ni * 16 + lm;
            const float bv = bias[cl];
#pragma unroll
            for (int mi = 0; mi < 4; ++mi) {
                const int row = M0 + wave_m + mi * 16 + lk * 4;
#pragma unroll
                for (int r = 0; r < 4; ++r)
                    outp[(size_t)(row + r) * ncols + cl] = acc[mi][ni][r] + bv;
            }
        }
    }
}

// ---------------------------------------------------------------------------
// Sampling v3: 2 queries per wave. lane = q2*32 + head*4 + d8g (4 lanes/head,
// 8 bf16 elems each -> 16B gathers serving 2 queries/instr). value is bf16
// [row][256] rows 512B. bf16->f32 by integer unpack. Output bf16x8 to
// swizzled fusedS rows.
// ---------------------------------------------------------------------------
__global__ __launch_bounds__(256) void sample_kernel(const char* __restrict__ valueB,
                                                     const float* __restrict__ offs,
                                                     const float* __restrict__ logits,
                                                     char* __restrict__ fusedS)
{
    const int wid  = (blockIdx.x << 2) + (threadIdx.x >> 6);  // 0..16383
    const int lane = threadIdx.x & 63;
    const int q2   = lane >> 5;
    const int row  = wid * 2 + q2;                // b*LQ + ql
    const int sub  = lane & 31;
    const int head = sub >> 2;
    const int d8   = (sub & 3) << 3;              // 0,8,16,24
    const int b    = row >> 13;
    const int pix  = row & 4095;
    const float fx0 = (float)(pix & 63);
    const float fy0 = (float)(pix >> 6);

    // softmax over this head's 8 logits (dup x4 lanes)
    const float* lg = logits + (size_t)row * 64 + head * 8;
    const float4 lgA = *(const float4*)lg;
    const float4 lgB = *(const float4*)(lg + 4);
    float e[8] = {lgA.x, lgA.y, lgA.z, lgA.w, lgB.x, lgB.y, lgB.z, lgB.w};
    float mx = e[0];
#pragma unroll
    for (int j = 1; j < 8; ++j) mx = fmaxf(mx, e[j]);
    float s = 0.f;
#pragma unroll
    for (int j = 0; j < 8; ++j) { e[j] = __expf(e[j] - mx); s += e[j]; }
    const float inv = 1.0f / s;

    const float* of = offs + (size_t)row * 128 + head * 16;
    float o[16];
#pragma unroll
    for (int j = 0; j < 4; ++j) {
        const float4 v4 = *(const float4*)(of + j * 4);
        o[j * 4 + 0] = v4.x; o[j * 4 + 1] = v4.y;
        o[j * 4 + 2] = v4.z; o[j * 4 + 3] = v4.w;
    }

    float acc[8] = {};
#pragma unroll
    for (int ll = 0; ll < 2; ++ll) {
        const char* vb = valueB + (((size_t)(b * LQ + ll * HW)) << 9) + head * 64 + d8 * 2;
#pragma unroll
        for (int p = 0; p < 4; ++p) {
            const float ox = o[ll * 8 + p * 2];
            const float oy = o[ll * 8 + p * 2 + 1];
            const float aw = e[ll * 4 + p] * inv;
            const float x = fx0 + ox;
            const float y = fy0 + oy;
            const float xf = floorf(x), yf = floorf(y);
            const int   xi = (int)xf,  yi = (int)yf;
            const float dx = x - xf,   dy = y - yf;
            float w00 = (1.f - dx) * (1.f - dy);
            float w10 = dx * (1.f - dy);
            float w01 = (1.f - dx) * dy;
            float w11 = dx * dy;
            const bool vx0 = (unsigned)xi       < 64u;
            const bool vx1 = (unsigned)(xi + 1) < 64u;
            const bool vy0 = (unsigned)yi       < 64u;
            const bool vy1 = (unsigned)(yi + 1) < 64u;
            const float u00 = (vx0 && vy0) ? aw * w00 : 0.f;
            const float u10 = (vx1 && vy0) ? aw * w10 : 0.f;
            const float u01 = (vx0 && vy1) ? aw * w01 : 0.f;
            const float u11 = (vx1 && vy1) ? aw * w11 : 0.f;
            const int xc0 = min(max(xi, 0), 63);
            const int xc1 = min(max(xi + 1, 0), 63);
            const int yc0 = min(max(yi, 0), 63) << 6;
            const int yc1 = min(max(yi + 1, 0), 63) << 6;
            const u32x4 g00 = *(const u32x4*)(vb + ((size_t)(yc0 + xc0) << 9));
            const u32x4 g10 = *(const u32x4*)(vb + ((size_t)(yc0 + xc1) << 9));
            const u32x4 g01 = *(const u32x4*)(vb + ((size_t)(yc1 + xc0) << 9));
            const u32x4 g11 = *(const u32x4*)(vb + ((size_t)(yc1 + xc1) << 9));
#pragma unroll
            for (int j = 0; j < 4; ++j) {
                const float l00 = __uint_as_float(g00[j] << 16);
                const float h00 = __uint_as_float(g00[j] & 0xffff0000u);
                const float l10 = __uint_as_float(g10[j] << 16);
                const float h10 = __uint_as_float(g10[j] & 0xffff0000u);
                const float l01 = __uint_as_float(g01[j] << 16);
                const float h01 = __uint_as_float(g01[j] & 0xffff0000u);
                const float l11 = __uint_as_float(g11[j] << 16);
                const float h11 = __uint_as_float(g11[j] & 0xffff0000u);
                acc[j * 2]     += u00 * l00 + u10 * l10 + u01 * l01 + u11 * l11;
                acc[j * 2 + 1] += u00 * h00 + u10 * h10 + u01 * h01 + u11 * h11;
            }
        }
    }
    bf16x8 ov;
#pragma unroll
    for (int j = 0; j < 8; ++j) ov[j] = (__bf16)acc[j];
    const int bo = (head * 64 + d8 * 2) ^ ((row & 7) << 4);
    *(bf16x8*)(fusedS + (size_t)row * 512 + bo) = ov;
}

// ---------------------------------------------------------------------------
// Output GEMM (MFMA): K=512 concat over the two halves (v+i sum absorbed);
// epilogue LDS-transpose -> coalesced fp32 stores along q.
// ---------------------------------------------------------------------------
__global__ __launch_bounds__(256) void mfma_out(const char* __restrict__ fusedS,
                                                const char* __restrict__ WoutT,
                                                const float* __restrict__ b_out,
                                                float* __restrict__ out)
{
    __shared__ char smem[24576];
    char* As = smem;
    char* Bs = smem + 16384;
    float* Tr = (float*)smem;

    const int M0 = blockIdx.x * 128;
    const int N0 = blockIdx.y * 64;
    const int bi = M0 >> 12;
    const int q0 = M0 & 4095;
    const int t = threadIdx.x;
    const int w = t >> 6;
    const int l = t & 63;
    const int lm = l & 15, lk = l >> 4;
    const int wave_m = (w >> 1) * 64;
    const int wave_n = (w & 1) * 32;

    f32x4 acc[4][2] = {};

    const char* Ab = As + (wave_m + lm) * 128;
    const char* Bb = Bs + (wave_n + lm) * 128;
    const int go0 = (lk ^ (l & 7)) * 16;
    const int go1 = go0 ^ 64;

    for (int kt = 0; kt < 8; ++kt) {
        __syncthreads();
        const int half = kt >> 2;
        const int kb   = (kt & 3) * 128;
#pragma unroll
        for (int c = 0; c < 4; ++c) {
            const char* g = fusedS + (size_t)(bi * LQ + half * HW + q0 + w * 32 + c * 8 + (l >> 3)) * 512
                          + kb + (l & 7) * 16;
            GLOAD16(g, As + (w * 4 + c) * 1024);
        }
#pragma unroll
        for (int c = 0; c < 2; ++c) {
            const char* g = WoutT + (size_t)(N0 + w * 16 + c * 8 + (l >> 3)) * 1024 + kt * 128 + (l & 7) * 16;
            GLOAD16(g, Bs + (w * 2 + c) * 1024);
        }
        __syncthreads();

        bf16x8 af[4], bb[2];
#pragma unroll
        for (int mi = 0; mi < 4; ++mi) af[mi] = *(const bf16x8*)(Ab + mi * 2048 + go0);
#pragma unroll
        for (int ni = 0; ni < 2; ++ni) bb[ni] = *(const bf16x8*)(Bb + ni * 2048 + go0);
#pragma unroll
        for (int mi = 0; mi < 4; ++mi)
#pragma unroll
            for (int ni = 0; ni < 2; ++ni)
                acc[mi][ni] = __builtin_amdgcn_mfma_f32_16x16x32_bf16(af[mi], bb[ni], acc[mi][ni], 0, 0, 0);
#pragma unroll
        for (int mi = 0; mi < 4; ++mi) af[mi] = *(const bf16x8*)(Ab + mi * 2048 + go1);
#pragma unroll
        for (int ni = 0; ni < 2; ++ni) bb[ni] = *(const bf16x8*)(Bb + ni * 2048 + go1);
#pragma unroll
        for (int mi = 0; mi < 4; ++mi)
#pragma unroll
            for (int ni = 0; ni < 2; ++ni)
                acc[mi][ni] = __builtin_amdgcn_mfma_f32_16x16x32_bf16(af[mi], bb[ni], acc[mi][ni], 0, 0, 0);
    }

    float bias2[2];
#pragma unroll
    for (int ni = 0; ni < 2; ++ni) bias2[ni] = 2.0f * b_out[N0 + wave_n + ni * 16 + lm];

#pragma unroll
    for (int h = 0; h < 2; ++h) {
        __syncthreads();
        if ((w >> 1) == h) {
#pragma unroll
            for (int mi = 0; mi < 4; ++mi)
#pragma unroll
                for (int ni = 0; ni < 2; ++ni)
#pragma unroll
                    for (int r = 0; r < 4; ++r)
                        Tr[(wave_n + ni * 16 + lm) * 68 + mi * 16 + lk * 4 + r] = acc[mi][ni][r] + bias2[ni];
        }
        __syncthreads();
        const int c  = t >> 2;
        const int qo = (t & 3) * 16;
        float* dst = out + ((size_t)(bi * DD + N0 + c)) * HW + q0 + h * 64 + qo;
        const float* sp = Tr + c * 68 + qo;
#pragma unroll
        for (int j = 0; j < 4; ++j)
            *(f32x4*)(dst + j * 4) = *(const f32x4*)(sp + j * 4);
    }
}

extern "C" void kernel_launch(void* const* d_in, const int* in_sizes, int n_in,
                              void* d_out, int out_size, void* d_ws, size_t ws_size,
                              hipStream_t stream) {
    const float* in_v    = (const float*)d_in[0];
    const float* in_i    = (const float*)d_in[1];
    const float* W_value = (const float*)d_in[2];
    const float* b_value = (const float*)d_in[3];
    const float* W_off   = (const float*)d_in[4];
    const float* b_off   = (const float*)d_in[5];
    const float* W_attn  = (const float*)d_in[6];
    const float* b_attn  = (const float*)d_in[7];
    const float* W_out   = (const float*)d_in[8];
    const float* b_out   = (const float*)d_in[9];
    float* out = (float*)d_out;

    char* ws = (char*)d_ws;
    __bf16* valueB = (__bf16*)(ws);                 // 16.78 MB bf16 [32768][512B]
    float*  off_ws = (float*)(ws + 16777216);       // 16.78 MB fp32
    float*  attn_ws= (float*)(ws + 33554432);       //  8.39 MB fp32
    char*   srcS   = ws + 41943040;                 // 16.78 MB bf16 [32768][512B]
    char*   fusedS = ws + 58720256;                 // 16.78 MB bf16 [32768][512B]
    char*   WcatT  = ws + 75497472;                 // 229 KB
    char*   WoutT  = ws + 75726848;                 // 256 KB

    prep_src<<<dim3(64, 4, 8), 256, 0, stream>>>(in_v, in_i, srcS);
    prep_w<<<120, 256, 0, stream>>>(W_value, W_off, W_attn, W_out, WcatT, WoutT);
    mfma_proj<<<dim3(256, 7), 256, 0, stream>>>(srcS, WcatT, b_value, b_off, b_attn,
                                                valueB, off_ws, attn_ws);
    sample_kernel<<<dim3(4096), 256, 0, stream>>>((const char*)valueB, off_ws, attn_ws, fusedS);
    mfma_out<<<dim3(128, 4), 256, 0, stream>>>(fusedS, WoutT, b_out, out);
}